// Round 1
// baseline (227.558 us; speedup 1.0000x reference)
//
#include <hip/hip_runtime.h>
#include <stdint.h>

#define S_ 8
#define N_ 4096
#define I_ 256
#define L_ 512
#define M_ 256
#define D_ 768   // I + L

typedef __bf16 bf16x8 __attribute__((ext_vector_type(8)));
typedef float f32x4 __attribute__((ext_vector_type(4)));
typedef unsigned short ushort_t;

__device__ __forceinline__ unsigned short f2bf(float f) {
  union { float f; uint32_t u; } c; c.f = f;
  uint32_t u = c.u;
  uint32_t r = u + 0x7FFFu + ((u >> 16) & 1u);
  return (unsigned short)(r >> 16);
}

__device__ __forceinline__ float fsigmoid(float x) {
  return 1.0f / (1.0f + __expf(-x));
}
__device__ __forceinline__ float ftanh(float x) {
  float ax = fabsf(x);
  float e = __expf(-2.0f * ax);
  float t = (1.0f - e) / (1.0f + e);
  return copysignf(t, x);
}

// global -> LDS direct copy, 16B per lane. LDS dest is wave-uniform base + lane*16.
#define GLD16(gsrc, ldst)                                                                  \
  __builtin_amdgcn_global_load_lds(                                                        \
      (const __attribute__((address_space(1))) uint32_t*)(uintptr_t)(gsrc),                \
      (__attribute__((address_space(3))) uint32_t*)(uintptr_t)(ldst), 16, 0, 0)

// ---------------- prep kernels ----------------

__global__ __launch_bounds__(256) void cast_bf16_kernel(const float* __restrict__ src,
                                                        ushort_t* __restrict__ dst, int n4) {
  int t = blockIdx.x * 256 + threadIdx.x;
  int stride = gridDim.x * 256;
  for (; t < n4; t += stride) {
    float4 v = ((const float4*)src)[t];
    ushort4 o;
    o.x = f2bf(v.x); o.y = f2bf(v.y); o.z = f2bf(v.z); o.w = f2bf(v.w);
    ((ushort4*)dst)[t] = o;
  }
}

// xh[s][n][0:256] = modulation[n][s*256 + :], xh[s][n][256:768] = h0[n][s*512 + :]
__global__ __launch_bounds__(256) void build_xh_kernel(const float* __restrict__ mod,
                                                       const float* __restrict__ h0,
                                                       ushort_t* __restrict__ xh) {
  int t = blockIdx.x * 256 + threadIdx.x;
  const int total = S_ * N_ * (D_ / 4);
  int stride = gridDim.x * 256;
  for (; t < total; t += stride) {
    int row = t / (D_ / 4);       // s*4096 + n
    int c = t - row * (D_ / 4);   // float4 chunk within row
    int s = row >> 12;
    int n = row & (N_ - 1);
    float4 v;
    if (c < I_ / 4)
      v = *(const float4*)(mod + (size_t)n * (S_ * I_) + s * I_ + c * 4);
    else
      v = *(const float4*)(h0 + (size_t)n * (S_ * L_) + s * L_ + (c - I_ / 4) * 4);
    ushort4 o;
    o.x = f2bf(v.x); o.y = f2bf(v.y); o.z = f2bf(v.z); o.w = f2bf(v.w);
    *(ushort4*)(xh + (size_t)t * 4) = o;
  }
}

// ---------------- gates GEMM + LSTM cell ----------------
// grid (N/128, L/64, S), 256 threads (4 waves). BK = 64.
// Computes 4 gate preacts for a 128x64 (n x l) tile, applies cell math,
// writes h_new bf16 to hout[s][n][l].
__global__ __launch_bounds__(256, 2) void gates_kernel(
    const ushort_t* __restrict__ xh,   // [S][N][D] bf16
    const ushort_t* __restrict__ w4,   // [4][S][L][D] bf16
    const float* __restrict__ bi, const float* __restrict__ bff,
    const float* __restrict__ bg, const float* __restrict__ bo,
    const float* __restrict__ c0,      // [N][S*L] f32
    ushort_t* __restrict__ hout)       // [S][N][L] bf16
{
  // A: 1024 chunks of 16B (128 rows x 8 chunks), B: 2048 chunks (4 gates x 64 rows x 8)
  __shared__ __align__(16) ushort_t smem[3072 * 8];
  const int tid = threadIdx.x;
  const int lane = tid & 63;
  const int w = tid >> 6;
  const int n0 = blockIdx.x * 128;
  const int l0 = blockIdx.y * 64;
  const int s = blockIdx.z;

  f32x4 acc[4][2][4];
  #pragma unroll
  for (int g = 0; g < 4; ++g)
    #pragma unroll
    for (int rt = 0; rt < 2; ++rt)
      #pragma unroll
      for (int ct = 0; ct < 4; ++ct) {
        f32x4 z = {0.f, 0.f, 0.f, 0.f};
        acc[g][rt][ct] = z;
      }

  const size_t xh_row0 = (size_t)(s * N_ + n0) * D_;

  for (int t = 0; t < D_ / 64; ++t) {
    const int k0 = t * 64;
    // stage A tile: LDS slot (r, c) holds global k-chunk (c ^ (r&7))  [XOR swizzle]
    #pragma unroll
    for (int it = 0; it < 4; ++it) {
      int chunk = it * 256 + tid;
      int r = chunk >> 3, c = chunk & 7;
      int cg = c ^ (r & 7);
      const ushort_t* src = xh + xh_row0 + (size_t)r * D_ + k0 + cg * 8;
      GLD16(src, &smem[(it * 256 + w * 64) * 8]);
    }
    // stage B tiles (4 gates)
    #pragma unroll
    for (int it = 0; it < 8; ++it) {
      int chunk = it * 256 + tid;
      int g = chunk >> 9;
      int rl = (chunk >> 3) & 63;
      int c = chunk & 7;
      int cg = c ^ (rl & 7);
      const ushort_t* src = w4 + ((size_t)((g * S_ + s) * L_ + l0 + rl)) * D_ + k0 + cg * 8;
      GLD16(src, &smem[(1024 + it * 256 + w * 64) * 8]);
    }
    __syncthreads();
    #pragma unroll
    for (int kk = 0; kk < 2; ++kk) {
      const int cc = kk * 4 + (lane >> 4);
      bf16x8 a[2];
      #pragma unroll
      for (int rt = 0; rt < 2; ++rt) {
        int r = w * 32 + rt * 16 + (lane & 15);
        a[rt] = *(const bf16x8*)&smem[(r * 8 + (cc ^ (r & 7))) * 8];
      }
      #pragma unroll
      for (int g = 0; g < 4; ++g) {
        #pragma unroll
        for (int ct = 0; ct < 4; ++ct) {
          int rl = ct * 16 + (lane & 15);
          bf16x8 b = *(const bf16x8*)&smem[(1024 + (g * 64 + rl) * 8 + (cc ^ (rl & 7))) * 8];
          acc[g][0][ct] = __builtin_amdgcn_mfma_f32_16x16x32_bf16(a[0], b, acc[g][0][ct], 0, 0, 0);
          acc[g][1][ct] = __builtin_amdgcn_mfma_f32_16x16x32_bf16(a[1], b, acc[g][1][ct], 0, 0, 0);
        }
      }
    }
    __syncthreads();
  }

  // epilogue: D frag layout col = lane&15, row = (lane>>4)*4 + j  [m89-verified]
  #pragma unroll
  for (int ct = 0; ct < 4; ++ct) {
    const int l = l0 + ct * 16 + (lane & 15);
    const float vbi = bi[s * L_ + l];
    const float vbf = bff[s * L_ + l];
    const float vbg = bg[s * L_ + l];
    const float vbo = bo[s * L_ + l];
    #pragma unroll
    for (int rt = 0; rt < 2; ++rt) {
      #pragma unroll
      for (int j = 0; j < 4; ++j) {
        const int n = n0 + w * 32 + rt * 16 + (lane >> 4) * 4 + j;
        const float c0v = c0[(size_t)n * (S_ * L_) + s * L_ + l];
        const float iv = fsigmoid(acc[0][rt][ct][j] + vbi);
        const float fv = fsigmoid(acc[1][rt][ct][j] + vbf);
        const float gv = ftanh(acc[2][rt][ct][j] + vbg);
        const float ov = fsigmoid(acc[3][rt][ct][j] + vbo);
        const float cn = fv * c0v + iv * gv;
        const float hn = ov * ftanh(cn);
        hout[(size_t)(s * N_ + n) * L_ + l] = f2bf(hn);
      }
    }
  }
}

// ---------------- output GEMM ----------------
// grid (N/128, M/64, S), 256 threads. y[n][s*256+m] = sum_l h[s][n][l]*Wy[s][m][l] + by[s][m]
__global__ __launch_bounds__(256, 2) void out_kernel(
    const ushort_t* __restrict__ h,    // [S][N][L] bf16
    const ushort_t* __restrict__ wy,   // [S][M][L] bf16
    const float* __restrict__ by,      // [S*M]
    float* __restrict__ out)           // [N][S*M]
{
  __shared__ __align__(16) ushort_t smem[1536 * 8];  // A 1024 slots + B 512 slots
  const int tid = threadIdx.x;
  const int lane = tid & 63;
  const int w = tid >> 6;
  const int n0 = blockIdx.x * 128;
  const int m0 = blockIdx.y * 64;
  const int s = blockIdx.z;

  f32x4 acc[2][4];
  #pragma unroll
  for (int rt = 0; rt < 2; ++rt)
    #pragma unroll
    for (int ct = 0; ct < 4; ++ct) {
      f32x4 z = {0.f, 0.f, 0.f, 0.f};
      acc[rt][ct] = z;
    }

  const size_t h_row0 = (size_t)(s * N_ + n0) * L_;

  for (int t = 0; t < L_ / 64; ++t) {
    const int k0 = t * 64;
    #pragma unroll
    for (int it = 0; it < 4; ++it) {
      int chunk = it * 256 + tid;
      int r = chunk >> 3, c = chunk & 7;
      int cg = c ^ (r & 7);
      const ushort_t* src = h + h_row0 + (size_t)r * L_ + k0 + cg * 8;
      GLD16(src, &smem[(it * 256 + w * 64) * 8]);
    }
    #pragma unroll
    for (int it = 0; it < 2; ++it) {
      int chunk = it * 256 + tid;
      int rl = chunk >> 3, c = chunk & 7;
      int cg = c ^ (rl & 7);
      const ushort_t* src = wy + ((size_t)(s * M_ + m0 + rl)) * L_ + k0 + cg * 8;
      GLD16(src, &smem[(1024 + it * 256 + w * 64) * 8]);
    }
    __syncthreads();
    #pragma unroll
    for (int kk = 0; kk < 2; ++kk) {
      const int cc = kk * 4 + (lane >> 4);
      bf16x8 a[2];
      #pragma unroll
      for (int rt = 0; rt < 2; ++rt) {
        int r = w * 32 + rt * 16 + (lane & 15);
        a[rt] = *(const bf16x8*)&smem[(r * 8 + (cc ^ (r & 7))) * 8];
      }
      #pragma unroll
      for (int ct = 0; ct < 4; ++ct) {
        int rl = ct * 16 + (lane & 15);
        bf16x8 b = *(const bf16x8*)&smem[(1024 + rl * 8 + (cc ^ (rl & 7))) * 8];
        acc[0][ct] = __builtin_amdgcn_mfma_f32_16x16x32_bf16(a[0], b, acc[0][ct], 0, 0, 0);
        acc[1][ct] = __builtin_amdgcn_mfma_f32_16x16x32_bf16(a[1], b, acc[1][ct], 0, 0, 0);
      }
    }
    __syncthreads();
  }

  #pragma unroll
  for (int ct = 0; ct < 4; ++ct) {
    const int m = m0 + ct * 16 + (lane & 15);
    const float vb = by[s * M_ + m];
    #pragma unroll
    for (int rt = 0; rt < 2; ++rt) {
      #pragma unroll
      for (int j = 0; j < 4; ++j) {
        const int n = n0 + w * 32 + rt * 16 + (lane >> 4) * 4 + j;
        out[(size_t)n * (S_ * M_) + s * M_ + m] = acc[rt][ct][j] + vb;
      }
    }
  }
}

// ---------------- launcher ----------------

extern "C" void kernel_launch(void* const* d_in, const int* in_sizes, int n_in,
                              void* d_out, int out_size, void* d_ws, size_t ws_size,
                              hipStream_t stream) {
  const float* mod = (const float*)d_in[0];
  const float* h0  = (const float*)d_in[1];
  const float* c0  = (const float*)d_in[2];
  const float* Wi  = (const float*)d_in[3];
  const float* bi  = (const float*)d_in[4];
  const float* Wf  = (const float*)d_in[5];
  const float* bf  = (const float*)d_in[6];
  const float* Wg  = (const float*)d_in[7];
  const float* bg  = (const float*)d_in[8];
  const float* Wo  = (const float*)d_in[9];
  const float* bo  = (const float*)d_in[10];
  const float* Wy  = (const float*)d_in[11];
  const float* by  = (const float*)d_in[12];
  float* out = (float*)d_out;

  ushort_t* ws = (ushort_t*)d_ws;
  ushort_t* xh   = ws;                                  // S*N*D      = 25,165,824 bf16
  ushort_t* w4   = xh  + (size_t)S_ * N_ * D_;          // 4*S*L*D    = 12,582,912
  ushort_t* wyb  = w4  + (size_t)4 * S_ * L_ * D_;      // S*M*L      =  1,048,576
  ushort_t* hbuf = wyb + (size_t)S_ * M_ * L_;          // S*N*L      = 16,777,216
  // total ws use: ~111.1 MB

  const int SLD4 = S_ * L_ * D_ / 4;  // 786432 float4 chunks per gate weight
  cast_bf16_kernel<<<512, 256, 0, stream>>>(Wi, w4 + 0 * (size_t)S_ * L_ * D_, SLD4);
  cast_bf16_kernel<<<512, 256, 0, stream>>>(Wf, w4 + 1 * (size_t)S_ * L_ * D_, SLD4);
  cast_bf16_kernel<<<512, 256, 0, stream>>>(Wg, w4 + 2 * (size_t)S_ * L_ * D_, SLD4);
  cast_bf16_kernel<<<512, 256, 0, stream>>>(Wo, w4 + 3 * (size_t)S_ * L_ * D_, SLD4);
  cast_bf16_kernel<<<256, 256, 0, stream>>>(Wy, wyb, S_ * M_ * L_ / 4);
  build_xh_kernel<<<2048, 256, 0, stream>>>(mod, h0, xh);
  gates_kernel<<<dim3(N_ / 128, L_ / 64, S_), 256, 0, stream>>>(xh, w4, bi, bf, bg, bo, c0, hbuf);
  out_kernel<<<dim3(N_ / 128, M_ / 64, S_), 256, 0, stream>>>(hbuf, wyb, by, out);
}

// Round 2
// 208.099 us; speedup vs baseline: 1.0935x; 1.0935x over previous
//
#include <hip/hip_runtime.h>
#include <stdint.h>

#define S_ 8
#define N_ 4096
#define I_ 256
#define L_ 512
#define M_ 256
#define D_ 768   // I + L
#define NTg 12   // 768/64 K-tiles

typedef __bf16 bf16x8 __attribute__((ext_vector_type(8)));
typedef float f32x4 __attribute__((ext_vector_type(4)));
typedef unsigned short ushort_t;

__device__ __forceinline__ unsigned short f2bf(float f) {
  union { float f; uint32_t u; } c; c.f = f;
  uint32_t u = c.u;
  uint32_t r = u + 0x7FFFu + ((u >> 16) & 1u);
  return (unsigned short)(r >> 16);
}

__device__ __forceinline__ float fsigmoid(float x) {
  return 1.0f / (1.0f + __expf(-x));
}
__device__ __forceinline__ float ftanh(float x) {
  float ax = fabsf(x);
  float e = __expf(-2.0f * ax);
  float t = (1.0f - e) / (1.0f + e);
  return copysignf(t, x);
}

#define GLD16(gsrc, ldst)                                                                  \
  __builtin_amdgcn_global_load_lds(                                                        \
      (const __attribute__((address_space(1))) uint32_t*)(uintptr_t)(gsrc),                \
      (__attribute__((address_space(3))) uint32_t*)(uintptr_t)(ldst), 16, 0, 0)

// ---------------- prep kernels ----------------

// One kernel casting Wi,Wf,Wg,Wo -> w4 [4][S][L][D] and Wy -> wyb, all f32->bf16.
__global__ __launch_bounds__(256) void cast_all_kernel(
    const float* __restrict__ Wi, const float* __restrict__ Wf,
    const float* __restrict__ Wg, const float* __restrict__ Wo,
    const float* __restrict__ Wy, ushort_t* __restrict__ w4,
    ushort_t* __restrict__ wyb) {
  const int GW = S_ * L_ * D_ / 4;          // float4 chunks per gate weight
  const int WYW = S_ * M_ * L_ / 4;
  const int TOT = 4 * GW + WYW;
  int t = blockIdx.x * 256 + threadIdx.x;
  int stride = gridDim.x * 256;
  for (; t < TOT; t += stride) {
    const float* src;
    ushort_t* dst;
    int off;
    if (t < 4 * GW) {
      int g = t / GW;
      off = t - g * GW;
      src = (g == 0) ? Wi : (g == 1) ? Wf : (g == 2) ? Wg : Wo;
      dst = w4 + (size_t)g * S_ * L_ * D_;
    } else {
      off = t - 4 * GW;
      src = Wy;
      dst = wyb;
    }
    float4 v = ((const float4*)src)[off];
    ushort4 o;
    o.x = f2bf(v.x); o.y = f2bf(v.y); o.z = f2bf(v.z); o.w = f2bf(v.w);
    ((ushort4*)dst)[off] = o;
  }
}

// xh[s][n][0:256] = modulation[n][s*256 + :], xh[s][n][256:768] = h0[n][s*512 + :]
__global__ __launch_bounds__(256) void build_xh_kernel(const float* __restrict__ mod,
                                                       const float* __restrict__ h0,
                                                       ushort_t* __restrict__ xh) {
  int t = blockIdx.x * 256 + threadIdx.x;
  const int total = S_ * N_ * (D_ / 4);
  int stride = gridDim.x * 256;
  for (; t < total; t += stride) {
    int row = t / (D_ / 4);
    int c = t - row * (D_ / 4);
    int s = row >> 12;
    int n = row & (N_ - 1);
    float4 v;
    if (c < I_ / 4)
      v = *(const float4*)(mod + (size_t)n * (S_ * I_) + s * I_ + c * 4);
    else
      v = *(const float4*)(h0 + (size_t)n * (S_ * L_) + s * L_ + (c - I_ / 4) * 4);
    ushort4 o;
    o.x = f2bf(v.x); o.y = f2bf(v.y); o.z = f2bf(v.z); o.w = f2bf(v.w);
    *(ushort4*)(xh + (size_t)t * 4) = o;
  }
}

// ---------------- gates: 8-phase 256x(64lx4g) GEMM + fused LSTM cell ----------------
// 512 threads (8 waves, 4 wm x 2 wl). Wave = 64n x 32l x 4 gates (lane-local cell math).
// LDS: buf0{A,B} + buf1{A,B}, 32KB each = 128 KB. Raw s_barrier + counted vmcnt(4).
// LDS chunk bases (16B units):
#define CA0 0
#define CB0 2048
#define CA1 4096
#define CB1 6144

// Stage one A half-tile (128 rows x 64 k) of K-tile `tile` into buf chunkbase.
#define STAGE_A_HALF(bufbase, half, tile) do {                                          \
    int t_ = (tile) < NTg ? (tile) : (NTg - 1);                                         \
    int k0_ = t_ << 6;                                                                  \
    _Pragma("unroll")                                                                   \
    for (int i_ = 0; i_ < 2; ++i_) {                                                    \
      int chunk_ = i_ * 512 + tid;                                                      \
      int r_ = chunk_ >> 3, sl_ = chunk_ & 7;                                           \
      int rf_ = (half) * 128 + r_;                                                      \
      const ushort_t* src_ = xh + xh_base + (size_t)rf_ * D_ + k0_ +                    \
                             ((sl_ ^ (rf_ & 7)) << 3);                                  \
      GLD16(src_, &smem[((bufbase) + (half) * 1024 + i_ * 512 + (w << 6)) * 8]);        \
    }                                                                                   \
  } while (0)

// Stage one B half-tile (gate pair `half`: rows half*128..+128 of [4g][64l]) .
#define STAGE_B_HALF(bufbase, half, tile) do {                                          \
    int t_ = (tile) < NTg ? (tile) : (NTg - 1);                                         \
    int k0_ = t_ << 6;                                                                  \
    _Pragma("unroll")                                                                   \
    for (int i_ = 0; i_ < 2; ++i_) {                                                    \
      int chunk_ = i_ * 512 + tid;                                                      \
      int r_ = chunk_ >> 3, sl_ = chunk_ & 7;                                           \
      int rB_ = (half) * 128 + r_;                                                      \
      int g_ = rB_ >> 6, ll_ = rB_ & 63;                                                \
      const ushort_t* src_ = w4 + ((size_t)((g_ * S_ + s) * L_) + l0 + ll_) * D_ +      \
                             k0_ + ((sl_ ^ (rB_ & 7)) << 3);                            \
      GLD16(src_, &smem[((bufbase) + (half) * 1024 + i_ * 512 + (w << 6)) * 8]);        \
    }                                                                                   \
  } while (0)

#define LOAD_A(kk, bufbase) do {                                                        \
    _Pragma("unroll")                                                                   \
    for (int rt_ = 0; rt_ < 4; ++rt_) {                                                 \
      int r_ = (wm << 6) + (rt_ << 4) + ln15;                                           \
      int cc_ = ((kk) << 2) + ln4;                                                      \
      a[kk][rt_] = *(const bf16x8*)&smem[((bufbase) + r_ * 8 + (cc_ ^ (r_ & 7))) * 8];  \
    }                                                                                   \
  } while (0)

#define LOAD_B(kk, gp, bufbase) do {                                                    \
    _Pragma("unroll")                                                                   \
    for (int gi_ = 0; gi_ < 2; ++gi_) {                                                 \
      _Pragma("unroll")                                                                 \
      for (int ct_ = 0; ct_ < 2; ++ct_) {                                               \
        int rB_ = (((gp) * 2 + gi_) << 6) + (wl << 5) + (ct_ << 4) + ln15;              \
        int cc_ = ((kk) << 2) + ln4;                                                    \
        bf[gi_][ct_] = *(const bf16x8*)&smem[((bufbase) + rB_ * 8 +                     \
                                              (cc_ ^ (rB_ & 7))) * 8];                  \
      }                                                                                 \
    }                                                                                   \
  } while (0)

#define DO_MFMA(kk, gp) do {                                                            \
    _Pragma("unroll")                                                                   \
    for (int rt_ = 0; rt_ < 4; ++rt_) {                                                 \
      _Pragma("unroll")                                                                 \
      for (int gi_ = 0; gi_ < 2; ++gi_) {                                               \
        _Pragma("unroll")                                                               \
        for (int ct_ = 0; ct_ < 2; ++ct_) {                                             \
          int cj_ = (((gp) * 2 + gi_) << 1) + ct_;                                      \
          acc[rt_][cj_] = __builtin_amdgcn_mfma_f32_16x16x32_bf16(                      \
              a[kk][rt_], bf[gi_][ct_], acc[rt_][cj_], 0, 0, 0);                        \
        }                                                                               \
      }                                                                                 \
    }                                                                                   \
  } while (0)

#define BAR() __builtin_amdgcn_s_barrier()
#define LGKM0() do { asm volatile("s_waitcnt lgkmcnt(0)");                              \
                     __builtin_amdgcn_sched_barrier(0); } while (0)
#define VMCNT4() do { asm volatile("s_waitcnt vmcnt(4)" ::: "memory");                  \
                      __builtin_amdgcn_sched_barrier(0); } while (0)

__global__ __launch_bounds__(512, 2) void gates8_kernel(
    const ushort_t* __restrict__ xh,   // [S][N][D] bf16
    const ushort_t* __restrict__ w4,   // [4][S][L][D] bf16
    const float* __restrict__ bi, const float* __restrict__ bff,
    const float* __restrict__ bg, const float* __restrict__ bo,
    const float* __restrict__ c0,      // [N][S*L] f32
    ushort_t* __restrict__ hout)       // [S][N][L] bf16
{
  __shared__ __align__(16) ushort_t smem[65536];  // 128 KB
  const int tid = threadIdx.x;
  const int lane = tid & 63;
  const int ln15 = lane & 15;
  const int ln4 = lane >> 4;
  const int w = tid >> 6;
  const int wm = w >> 1;
  const int wl = w & 1;

  // XCD-aware bijective swizzle over 1024 blocks (1024 % 8 == 0)
  int bid = blockIdx.x;
  int swz = (bid & 7) * 128 + (bid >> 3);
  const int s = swz >> 7;           // 128 blocks per stream
  const int r = swz & 127;
  const int n0 = (r >> 3) << 8;     // 16 n-blocks of 256
  const int l0 = (r & 7) << 6;      // 8 l-blocks of 64

  const size_t xh_base = (size_t)(s * N_ + n0) * D_;

  f32x4 acc[4][8];
  #pragma unroll
  for (int i = 0; i < 4; ++i)
    #pragma unroll
    for (int j = 0; j < 8; ++j) {
      f32x4 z = {0.f, 0.f, 0.f, 0.f};
      acc[i][j] = z;
    }

  bf16x8 a[2][4];
  bf16x8 bf[2][2];

  // Prologue: tile0 (4 halves -> buf0), tile1 A halves -> buf1. 12 loads in flight.
  STAGE_A_HALF(CA0, 0, 0);
  STAGE_A_HALF(CA0, 1, 0);
  STAGE_B_HALF(CB0, 0, 0);
  STAGE_B_HALF(CB0, 1, 0);
  STAGE_A_HALF(CA1, 0, 1);
  STAGE_A_HALF(CA1, 1, 1);

  for (int it = 0; it < NTg / 2; ++it) {
    const int T = 2 * it;
    // ---- P0 (switch to buf0: vmcnt ensures own tile-T stages landed; barrier
    //      makes it all-waves; reads after the barrier) ----
    VMCNT4();
    STAGE_B_HALF(CB1, 0, T + 1);
    BAR();
    LOAD_A(0, CA0); LOAD_B(0, 0, CB0);
    LGKM0();
    __builtin_amdgcn_s_setprio(1); DO_MFMA(0, 0); __builtin_amdgcn_s_setprio(0);
    BAR();
    // ---- P1 ----
    LOAD_A(1, CA0); LOAD_B(1, 0, CB0);
    STAGE_B_HALF(CB1, 1, T + 1);
    BAR();
    LGKM0();
    __builtin_amdgcn_s_setprio(1); DO_MFMA(1, 0); __builtin_amdgcn_s_setprio(0);
    BAR();
    // ---- P2 ----
    LOAD_B(0, 1, CB0);
    STAGE_A_HALF(CA0, 0, T + 2);
    BAR();
    LGKM0();
    __builtin_amdgcn_s_setprio(1); DO_MFMA(0, 1); __builtin_amdgcn_s_setprio(0);
    BAR();
    // ---- P3 ----
    LOAD_B(1, 1, CB0);
    STAGE_A_HALF(CA0, 1, T + 2);
    BAR();
    LGKM0();
    __builtin_amdgcn_s_setprio(1); DO_MFMA(1, 1); __builtin_amdgcn_s_setprio(0);
    BAR();
    // ---- P4 (switch to buf1) ----
    VMCNT4();
    STAGE_B_HALF(CB0, 0, T + 2);
    BAR();
    LOAD_A(0, CA1); LOAD_B(0, 0, CB1);
    LGKM0();
    __builtin_amdgcn_s_setprio(1); DO_MFMA(0, 0); __builtin_amdgcn_s_setprio(0);
    BAR();
    // ---- P5 ----
    LOAD_A(1, CA1); LOAD_B(1, 0, CB1);
    STAGE_B_HALF(CB0, 1, T + 2);
    BAR();
    LGKM0();
    __builtin_amdgcn_s_setprio(1); DO_MFMA(1, 0); __builtin_amdgcn_s_setprio(0);
    BAR();
    // ---- P6 ----
    LOAD_B(0, 1, CB1);
    STAGE_A_HALF(CA1, 0, T + 3);
    BAR();
    LGKM0();
    __builtin_amdgcn_s_setprio(1); DO_MFMA(0, 1); __builtin_amdgcn_s_setprio(0);
    BAR();
    // ---- P7 ----
    LOAD_B(1, 1, CB1);
    STAGE_A_HALF(CA1, 1, T + 3);
    BAR();
    LGKM0();
    __builtin_amdgcn_s_setprio(1); DO_MFMA(1, 1); __builtin_amdgcn_s_setprio(0);
    BAR();
  }

  // drain outstanding garbage stages before LDS dealloc / endpgm
  asm volatile("s_waitcnt vmcnt(0)" ::: "memory");

  // Epilogue: all 4 gates lane-local in acc[rt][g*2+ct].
  #pragma unroll
  for (int ct = 0; ct < 2; ++ct) {
    const int l = l0 + (wl << 5) + (ct << 4) + ln15;
    const float vbi = bi[s * L_ + l];
    const float vbf = bff[s * L_ + l];
    const float vbg = bg[s * L_ + l];
    const float vbo = bo[s * L_ + l];
    #pragma unroll
    for (int rt = 0; rt < 4; ++rt) {
      #pragma unroll
      for (int j = 0; j < 4; ++j) {
        const int n = n0 + (wm << 6) + (rt << 4) + (ln4 << 2) + j;
        const float c0v = c0[(size_t)n * (S_ * L_) + s * L_ + l];
        const float iv = fsigmoid(acc[rt][0 + ct][j] + vbi);
        const float fv = fsigmoid(acc[rt][2 + ct][j] + vbf);
        const float gv = ftanh(acc[rt][4 + ct][j] + vbg);
        const float ov = fsigmoid(acc[rt][6 + ct][j] + vbo);
        const float cn = fv * c0v + iv * gv;
        const float hn = ov * ftanh(cn);
        hout[(size_t)(s * N_ + n) * L_ + l] = f2bf(hn);
      }
    }
  }
}

// ---------------- output GEMM (round-1, verified) ----------------
__global__ __launch_bounds__(256, 2) void out_kernel(
    const ushort_t* __restrict__ h,    // [S][N][L] bf16
    const ushort_t* __restrict__ wy,   // [S][M][L] bf16
    const float* __restrict__ by,      // [S*M]
    float* __restrict__ out)           // [N][S*M]
{
  __shared__ __align__(16) ushort_t smem[1536 * 8];
  const int tid = threadIdx.x;
  const int lane = tid & 63;
  const int w = tid >> 6;
  const int n0 = blockIdx.x * 128;
  const int m0 = blockIdx.y * 64;
  const int s = blockIdx.z;

  f32x4 acc[2][4];
  #pragma unroll
  for (int rt = 0; rt < 2; ++rt)
    #pragma unroll
    for (int ct = 0; ct < 4; ++ct) {
      f32x4 z = {0.f, 0.f, 0.f, 0.f};
      acc[rt][ct] = z;
    }

  const size_t h_row0 = (size_t)(s * N_ + n0) * L_;

  for (int t = 0; t < L_ / 64; ++t) {
    const int k0 = t * 64;
    #pragma unroll
    for (int it = 0; it < 4; ++it) {
      int chunk = it * 256 + tid;
      int r = chunk >> 3, c = chunk & 7;
      int cg = c ^ (r & 7);
      const ushort_t* src = h + h_row0 + (size_t)r * L_ + k0 + cg * 8;
      GLD16(src, &smem[(it * 256 + w * 64) * 8]);
    }
    #pragma unroll
    for (int it = 0; it < 2; ++it) {
      int chunk = it * 256 + tid;
      int rl = chunk >> 3, c = chunk & 7;
      int cg = c ^ (rl & 7);
      const ushort_t* src = wy + ((size_t)(s * M_ + m0 + rl)) * L_ + k0 + cg * 8;
      GLD16(src, &smem[(1024 + it * 256 + w * 64) * 8]);
    }
    __syncthreads();
    #pragma unroll
    for (int kk = 0; kk < 2; ++kk) {
      const int cc = kk * 4 + (lane >> 4);
      bf16x8 av[2];
      #pragma unroll
      for (int rt = 0; rt < 2; ++rt) {
        int rr = w * 32 + rt * 16 + (lane & 15);
        av[rt] = *(const bf16x8*)&smem[(rr * 8 + (cc ^ (rr & 7))) * 8];
      }
      #pragma unroll
      for (int ct = 0; ct < 4; ++ct) {
        int rl = ct * 16 + (lane & 15);
        bf16x8 b = *(const bf16x8*)&smem[(1024 + rl * 8 + (cc ^ (rl & 7))) * 8];
        acc[0][ct] = __builtin_amdgcn_mfma_f32_16x16x32_bf16(av[0], b, acc[0][ct], 0, 0, 0);
        acc[1][ct] = __builtin_amdgcn_mfma_f32_16x16x32_bf16(av[1], b, acc[1][ct], 0, 0, 0);
      }
    }
    __syncthreads();
  }

  #pragma unroll
  for (int ct = 0; ct < 4; ++ct) {
    const int m = m0 + ct * 16 + (lane & 15);
    const float vb = by[s * M_ + m];
    #pragma unroll
    for (int rt = 0; rt < 2; ++rt) {
      #pragma unroll
      for (int j = 0; j < 4; ++j) {
        const int n = n0 + w * 32 + rt * 16 + (lane >> 4) * 4 + j;
        out[(size_t)n * (S_ * M_) + s * M_ + m] = acc[rt][ct][j] + vb;
      }
    }
  }
}

// ---------------- launcher ----------------

extern "C" void kernel_launch(void* const* d_in, const int* in_sizes, int n_in,
                              void* d_out, int out_size, void* d_ws, size_t ws_size,
                              hipStream_t stream) {
  const float* mod = (const float*)d_in[0];
  const float* h0  = (const float*)d_in[1];
  const float* c0  = (const float*)d_in[2];
  const float* Wi  = (const float*)d_in[3];
  const float* bi  = (const float*)d_in[4];
  const float* Wf  = (const float*)d_in[5];
  const float* bf  = (const float*)d_in[6];
  const float* Wg  = (const float*)d_in[7];
  const float* bg  = (const float*)d_in[8];
  const float* Wo  = (const float*)d_in[9];
  const float* bo  = (const float*)d_in[10];
  const float* Wy  = (const float*)d_in[11];
  const float* by  = (const float*)d_in[12];
  float* out = (float*)d_out;

  ushort_t* ws = (ushort_t*)d_ws;
  ushort_t* xh   = ws;                                  // S*N*D bf16
  ushort_t* w4   = xh  + (size_t)S_ * N_ * D_;          // 4*S*L*D
  ushort_t* wyb  = w4  + (size_t)4 * S_ * L_ * D_;      // S*M*L
  ushort_t* hbuf = wyb + (size_t)S_ * M_ * L_;          // S*N*L

  cast_all_kernel<<<2048, 256, 0, stream>>>(Wi, Wf, Wg, Wo, Wy, w4, wyb);
  build_xh_kernel<<<2048, 256, 0, stream>>>(mod, h0, xh);
  gates8_kernel<<<1024, 512, 0, stream>>>(xh, w4, bi, bf, bg, bo, c0, hbuf);
  out_kernel<<<dim3(N_ / 128, M_ / 64, S_), 256, 0, stream>>>(hbuf, wyb, by, out);
}